// Round 5
// baseline (278.330 us; speedup 1.0000x reference)
//
#include <hip/hip_runtime.h>

// RES=[64,128,256,512,1024], NF=8, NC=2, P=1e6. out[p*40 + lvl*8 + c], fp32.
//
// Pipeline (all per-call, deterministic output):
//  1. absmax_fused + reduce_scales  -> per-level int8 scale
//  2. quant_fused                   -> int8 channel-last tables (uint2/pixel)
//  3. zero_hist / hist / scan / scatter -> counting sort of points into
//     4096 Morton buckets (64x64 grid); emits perm[] + sorted normalized xy
//  4. sample: 2 sorted points/thread, depth-2 level pipeline; wave lanes are
//     spatial neighbors -> gathers coalesce/L1-hit; writes scatter via perm.
//
// d_ws layout (bytes):
//   deq[8] f32      @ 0
//   inv[8] f32      @ 32
//   partials[5456]  @ 64
//   hist[4096]      @ 24576
//   starts[4096]    @ 40960
//   cursor[4096]    @ 57344
//   perm[~1M]       @ 131072
//   sortedxy[~1M]   @ 8388608   (float2, pre-normalized to [-1,1])
//   tables          @ 17301504  (uint2 per pixel, levels back-to-back)

#define WS_PART 64
#define WS_HIST 24576
#define WS_START 40960
#define WS_CURS 57344
#define WS_PERM 131072
#define WS_SXY 8388608
#define WS_TAB 17301504
#define NBUCK 4096

// ---- absmax stage 1 ----
__global__ __launch_bounds__(256) void absmax_fused_kernel(
    const float* __restrict__ s0, const float* __restrict__ s1,
    const float* __restrict__ s2, const float* __restrict__ s3,
    const float* __restrict__ s4, unsigned* __restrict__ partials) {
  __shared__ unsigned red[4];
  int b = blockIdx.x;
  const float* src; int n4; int lb; int nb;
  if (b < 16)        { src = s0; n4 = 16384;   lb = 0;    nb = 16; }
  else if (b < 80)   { src = s1; n4 = 65536;   lb = 16;   nb = 64; }
  else if (b < 336)  { src = s2; n4 = 262144;  lb = 80;   nb = 256; }
  else if (b < 1360) { src = s3; n4 = 1048576; lb = 336;  nb = 1024; }
  else               { src = s4; n4 = 4194304; lb = 1360; nb = 4096; }
  int local = b - lb;
  unsigned m = 0;
  for (int k = local * 256 + threadIdx.x; k < n4; k += nb * 256) {
    float4 v = ((const float4*)src)[k];
    unsigned a = __float_as_uint(v.x) & 0x7FFFFFFFu;
    unsigned c = __float_as_uint(v.y) & 0x7FFFFFFFu;
    unsigned d = __float_as_uint(v.z) & 0x7FFFFFFFu;
    unsigned e = __float_as_uint(v.w) & 0x7FFFFFFFu;
    m = max(m, max(max(a, c), max(d, e)));
  }
#pragma unroll
  for (int off = 32; off; off >>= 1)
    m = max(m, (unsigned)__shfl_xor((int)m, off));
  if ((threadIdx.x & 63) == 0) red[threadIdx.x >> 6] = m;
  __syncthreads();
  if (threadIdx.x == 0)
    partials[b] = max(max(red[0], red[1]), max(red[2], red[3]));
}

__global__ __launch_bounds__(256) void reduce_scales_kernel(
    const unsigned* __restrict__ partials, float* __restrict__ deq,
    float* __restrict__ inv) {
  __shared__ unsigned red[4];
  const int lo[5] = {0, 16, 80, 336, 1360};
  const int hi[5] = {16, 80, 336, 1360, 5456};
  for (int l = 0; l < 5; ++l) {
    unsigned m = 0;
    for (int i = lo[l] + (int)threadIdx.x; i < hi[l]; i += 256)
      m = max(m, partials[i]);
#pragma unroll
    for (int off = 32; off; off >>= 1)
      m = max(m, (unsigned)__shfl_xor((int)m, off));
    if ((threadIdx.x & 63) == 0) red[threadIdx.x >> 6] = m;
    __syncthreads();
    if (threadIdx.x == 0) {
      unsigned r = max(max(red[0], red[1]), max(red[2], red[3]));
      float s = __uint_as_float(r);
      if (!(s > 0.0f)) s = 1e-20f;
      deq[l] = s / 127.0f;
      inv[l] = 127.0f / s;
    }
    __syncthreads();
  }
}

// ---- quantize ----
__global__ __launch_bounds__(256) void quant_fused_kernel(
    const float* __restrict__ s0, const float* __restrict__ s1,
    const float* __restrict__ s2, const float* __restrict__ s3,
    const float* __restrict__ s4, uint2* __restrict__ tb,
    const float* __restrict__ invp) {
  int b = blockIdx.x;
  const float* src; int HW; int lb; int l; size_t toff;
  if (b < 32)        { src = s0; HW = 4096;    lb = 0;    l = 0; toff = 0; }
  else if (b < 160)  { src = s1; HW = 16384;   lb = 32;   l = 1; toff = 8192; }
  else if (b < 672)  { src = s2; HW = 65536;   lb = 160;  l = 2; toff = 40960; }
  else if (b < 2720) { src = s3; HW = 262144;  lb = 672;  l = 3; toff = 172032; }
  else               { src = s4; HW = 1048576; lb = 2720; l = 4; toff = 696320; }
  int i = (b - lb) * 256 + (int)threadIdx.x;
  float sc = invp[l];
  int cell = i / HW;
  int pix = i - cell * HW;
  const float* s = src + (size_t)cell * 8u * (size_t)HW + (size_t)pix;
  unsigned lov = 0, hiv = 0;
#pragma unroll
  for (int c = 0; c < 4; ++c) {
    int q = (int)rintf(s[(size_t)c * HW] * sc);
    q = min(max(q, -127), 127);
    lov |= ((unsigned)(q & 0xFF)) << (8 * c);
  }
#pragma unroll
  for (int c = 0; c < 4; ++c) {
    int q = (int)rintf(s[(size_t)(c + 4) * HW] * sc);
    q = min(max(q, -127), 127);
    hiv |= ((unsigned)(q & 0xFF)) << (8 * c);
  }
  tb[toff + (size_t)i] = make_uint2(lov, hiv);
}

// ---- counting sort into Morton buckets ----
__device__ __forceinline__ unsigned part1by1(unsigned v) {
  v &= 0x0000FFFFu;
  v = (v | (v << 8)) & 0x00FF00FFu;
  v = (v | (v << 4)) & 0x0F0F0F0Fu;
  v = (v | (v << 2)) & 0x33333333u;
  v = (v | (v << 1)) & 0x55555555u;
  return v;
}

__device__ __forceinline__ int bucket_of(float xv, float yv) {
  int bx = (int)(xv * 64.0f);
  int by = (int)(yv * 64.0f);
  bx = min(max(bx, 0), 63);
  by = min(max(by, 0), 63);
  return (int)(part1by1((unsigned)bx) | (part1by1((unsigned)by) << 1));
}

__global__ __launch_bounds__(256) void zero_hist_kernel(unsigned* __restrict__ hist) {
  int i = blockIdx.x * 256 + (int)threadIdx.x;
  if (i < NBUCK) hist[i] = 0u;
}

__global__ __launch_bounds__(256) void hist_kernel(
    const float* __restrict__ x, const float* __restrict__ y, int P,
    unsigned* __restrict__ hist) {
  int stride = gridDim.x * blockDim.x;
  for (int p = blockIdx.x * blockDim.x + (int)threadIdx.x; p < P; p += stride)
    atomicAdd(&hist[bucket_of(x[p], y[p])], 1u);
}

// one block, 256 threads: exclusive scan of hist[4096] -> starts, cursor
__global__ __launch_bounds__(256) void scan_kernel(
    const unsigned* __restrict__ hist, unsigned* __restrict__ starts,
    unsigned* __restrict__ cursor) {
  __shared__ unsigned sums[256];
  int t = (int)threadIdx.x;
  unsigned local[16];
  unsigned s = 0;
#pragma unroll
  for (int i = 0; i < 16; ++i) { local[i] = s; s += hist[t * 16 + i]; }
  sums[t] = s;
  __syncthreads();
  // Hillis-Steele over 256 block sums -> inclusive
  for (int off = 1; off < 256; off <<= 1) {
    unsigned v = (t >= off) ? sums[t - off] : 0u;
    __syncthreads();
    sums[t] += v;
    __syncthreads();
  }
  unsigned base = (t == 0) ? 0u : sums[t - 1];
#pragma unroll
  for (int i = 0; i < 16; ++i) {
    unsigned v = base + local[i];
    starts[t * 16 + i] = v;
    cursor[t * 16 + i] = v;
  }
}

__global__ __launch_bounds__(256) void scatter_kernel(
    const float* __restrict__ x, const float* __restrict__ y, int P,
    unsigned* __restrict__ cursor, int* __restrict__ perm,
    float2* __restrict__ sxy) {
  int stride = gridDim.x * blockDim.x;
  for (int p = blockIdx.x * blockDim.x + (int)threadIdx.x; p < P; p += stride) {
    float xv = x[p], yv = y[p];
    int b = bucket_of(xv, yv);
    unsigned slot = atomicAdd(&cursor[b], 1u);
    perm[slot] = p;
    sxy[slot] = make_float2(xv * 2.0f - 1.0f, yv * 2.0f - 1.0f);
  }
}

// ---- sampling ----
template <int W>
__device__ __forceinline__ void level_idx(float xn, float yn, int* __restrict__ idx) {
#pragma unroll
  for (int cell = 0; cell < 2; ++cell) {
    const float off = 0.5f * (float)cell;
    float ix = (xn + 1.0f) * 0.5f * (float)(W - 1) + off;
    float iy = (yn + 1.0f) * 0.5f * (float)(W - 1) + off;
    int xi = (int)floorf(ix);
    int yi = (int)floorf(iy);
    xi = min(max(xi, 0), W - 1);
    yi = min(max(yi, 0), W - 1);
    int xb = min(xi + 1, W - 1);
    int yb = min(yi + 1, W - 1);
    int base = cell * W * W;
    idx[cell * 4 + 0] = base + yi * W + xi;
    idx[cell * 4 + 1] = base + yi * W + xb;
    idx[cell * 4 + 2] = base + yb * W + xi;
    idx[cell * 4 + 3] = base + yb * W + xb;
  }
}

template <int W>
__device__ __forceinline__ void level_weights(float xn, float yn, float* __restrict__ wgt) {
#pragma unroll
  for (int cell = 0; cell < 2; ++cell) {
    const float off = 0.5f * (float)cell;
    float ix = (xn + 1.0f) * 0.5f * (float)(W - 1) + off;
    float iy = (yn + 1.0f) * 0.5f * (float)(W - 1) + off;
    float wx = ix - floorf(ix);
    float wy = iy - floorf(iy);
    wgt[cell * 4 + 0] = (1.0f - wx) * (1.0f - wy);
    wgt[cell * 4 + 1] = wx * (1.0f - wy);
    wgt[cell * 4 + 2] = (1.0f - wx) * wy;
    wgt[cell * 4 + 3] = wx * wy;
  }
}

__device__ __forceinline__ void load8(const uint2* __restrict__ t,
                                      const int* __restrict__ idx,
                                      uint2* __restrict__ v) {
#pragma unroll
  for (int i = 0; i < 8; ++i) v[i] = t[idx[i]];
}

__device__ __forceinline__ void consume8(const uint2* __restrict__ v,
                                         const float* __restrict__ wgt, float deq,
                                         float* __restrict__ res) {
  float acc[8];
#pragma unroll
  for (int i = 0; i < 8; ++i) acc[i] = 0.0f;
#pragma unroll
  for (int i = 0; i < 8; ++i) {
    float w = wgt[i];
    unsigned lo = v[i].x, hi = v[i].y;
#pragma unroll
    for (int c = 0; c < 4; ++c)
      acc[c] = fmaf((float)(signed char)(lo >> (8 * c)), w, acc[c]);
#pragma unroll
    for (int c = 0; c < 4; ++c)
      acc[4 + c] = fmaf((float)(signed char)(hi >> (8 * c)), w, acc[4 + c]);
  }
#pragma unroll
  for (int i = 0; i < 8; ++i) res[i] = acc[i] * deq;
}

__device__ __forceinline__ void store8(float* __restrict__ o, const float* __restrict__ r) {
  ((float4*)o)[0] = make_float4(r[0], r[1], r[2], r[3]);
  ((float4*)o)[1] = make_float4(r[4], r[5], r[6], r[7]);
}

__global__ __launch_bounds__(256) void sample_kernel_sorted(
    const float2* __restrict__ sxy, const int* __restrict__ perm,
    const uint2* __restrict__ t0, const uint2* __restrict__ t1,
    const uint2* __restrict__ t2, const uint2* __restrict__ t3,
    const uint2* __restrict__ t4, const float* __restrict__ deqs,
    float* __restrict__ out, int P) {
  int i0 = blockIdx.x * 512 + (int)threadIdx.x;
  int i1 = i0 + 256;
  bool v0 = i0 < P, v1 = i1 < P;
  float2 c0 = v0 ? sxy[i0] : make_float2(0.0f, 0.0f);
  float2 c1 = v1 ? sxy[i1] : make_float2(0.0f, 0.0f);
  int q0 = v0 ? perm[i0] : 0;
  int q1 = v1 ? perm[i1] : 0;
  float xn0 = c0.x, yn0 = c0.y, xn1 = c1.x, yn1 = c1.y;
  float d0 = deqs[0], d1 = deqs[1], d2 = deqs[2], d3 = deqs[3], d4 = deqs[4];
  float* o0 = out + (size_t)q0 * 40u;
  float* o1 = out + (size_t)q1 * 40u;

  int ia[8];
  uint2 a0[8], a1[8], b0[8], b1[8];
  float wg[8], res[8];

  level_idx<64>(xn0, yn0, ia);   load8(t0, ia, a0);
  level_idx<64>(xn1, yn1, ia);   load8(t0, ia, a1);
  level_idx<128>(xn0, yn0, ia);  load8(t1, ia, b0);
  level_idx<128>(xn1, yn1, ia);  load8(t1, ia, b1);

  level_weights<64>(xn0, yn0, wg);  consume8(a0, wg, d0, res); if (v0) store8(o0 + 0, res);
  level_weights<64>(xn1, yn1, wg);  consume8(a1, wg, d0, res); if (v1) store8(o1 + 0, res);
  level_idx<256>(xn0, yn0, ia);  load8(t2, ia, a0);
  level_idx<256>(xn1, yn1, ia);  load8(t2, ia, a1);

  level_weights<128>(xn0, yn0, wg); consume8(b0, wg, d1, res); if (v0) store8(o0 + 8, res);
  level_weights<128>(xn1, yn1, wg); consume8(b1, wg, d1, res); if (v1) store8(o1 + 8, res);
  level_idx<512>(xn0, yn0, ia);  load8(t3, ia, b0);
  level_idx<512>(xn1, yn1, ia);  load8(t3, ia, b1);

  level_weights<256>(xn0, yn0, wg); consume8(a0, wg, d2, res); if (v0) store8(o0 + 16, res);
  level_weights<256>(xn1, yn1, wg); consume8(a1, wg, d2, res); if (v1) store8(o1 + 16, res);
  level_idx<1024>(xn0, yn0, ia); load8(t4, ia, a0);
  level_idx<1024>(xn1, yn1, ia); load8(t4, ia, a1);

  level_weights<512>(xn0, yn0, wg);  consume8(b0, wg, d3, res); if (v0) store8(o0 + 24, res);
  level_weights<512>(xn1, yn1, wg);  consume8(b1, wg, d3, res); if (v1) store8(o1 + 24, res);
  level_weights<1024>(xn0, yn0, wg); consume8(a0, wg, d4, res); if (v0) store8(o0 + 32, res);
  level_weights<1024>(xn1, yn1, wg); consume8(a1, wg, d4, res); if (v1) store8(o1 + 32, res);
}

// ---- fallback: native layout fp32 direct ----
template <int W>
__device__ __forceinline__ void sample_level_direct(
    const float* __restrict__ t, float xv, float yv, float* __restrict__ o) {
  float acc[8];
#pragma unroll
  for (int i = 0; i < 8; ++i) acc[i] = 0.0f;
  float xn = xv * 2.0f - 1.0f;
  float yn = yv * 2.0f - 1.0f;
#pragma unroll
  for (int cell = 0; cell < 2; ++cell) {
    const float off = 0.5f * (float)cell;
    float ix = (xn + 1.0f) * 0.5f * (float)(W - 1) + off;
    float iy = (yn + 1.0f) * 0.5f * (float)(W - 1) + off;
    float x0f = floorf(ix), y0f = floorf(iy);
    float wx = ix - x0f, wy = iy - y0f;
    int x0 = (int)x0f; x0 = min(max(x0, 0), W - 1);
    int y0 = (int)y0f; y0 = min(max(y0, 0), W - 1);
    int x1 = min(x0 + 1, W - 1);
    int y1 = min(y0 + 1, W - 1);
    float w00 = (1.0f - wx) * (1.0f - wy);
    float w01 = wx * (1.0f - wy);
    float w10 = (1.0f - wx) * wy;
    float w11 = wx * wy;
    const float* b = t + (size_t)cell * 8u * (size_t)W * (size_t)W;
    size_t i00 = (size_t)y0 * W + x0;
    size_t i01 = (size_t)y0 * W + x1;
    size_t i10 = (size_t)y1 * W + x0;
    size_t i11 = (size_t)y1 * W + x1;
#pragma unroll
    for (int c = 0; c < 8; ++c) {
      const float* pc = b + (size_t)c * (size_t)W * (size_t)W;
      acc[c] += pc[i00] * w00 + pc[i01] * w01 + pc[i10] * w10 + pc[i11] * w11;
    }
  }
#pragma unroll
  for (int i = 0; i < 8; ++i) o[i] = acc[i];
}

__global__ __launch_bounds__(256) void sample_kernel_direct(
    const float* __restrict__ x, const float* __restrict__ y,
    const float* __restrict__ t0, const float* __restrict__ t1,
    const float* __restrict__ t2, const float* __restrict__ t3,
    const float* __restrict__ t4, float* __restrict__ out, int P) {
  int p = blockIdx.x * blockDim.x + threadIdx.x;
  if (p >= P) return;
  float xv = x[p];
  float yv = y[p];
  float o[8];
  float* orow = out + (size_t)p * 40u;
  sample_level_direct<64>(t0, xv, yv, o);
#pragma unroll
  for (int i = 0; i < 8; ++i) orow[0 + i] = o[i];
  sample_level_direct<128>(t1, xv, yv, o);
#pragma unroll
  for (int i = 0; i < 8; ++i) orow[8 + i] = o[i];
  sample_level_direct<256>(t2, xv, yv, o);
#pragma unroll
  for (int i = 0; i < 8; ++i) orow[16 + i] = o[i];
  sample_level_direct<512>(t3, xv, yv, o);
#pragma unroll
  for (int i = 0; i < 8; ++i) orow[24 + i] = o[i];
  sample_level_direct<1024>(t4, xv, yv, o);
#pragma unroll
  for (int i = 0; i < 8; ++i) orow[32 + i] = o[i];
}

extern "C" void kernel_launch(void* const* d_in, const int* in_sizes, int n_in,
                              void* d_out, int out_size, void* d_ws, size_t ws_size,
                              hipStream_t stream) {
  const float* x = (const float*)d_in[0];
  const float* y = (const float*)d_in[1];
  const float* tabs[5] = {(const float*)d_in[2], (const float*)d_in[3],
                          (const float*)d_in[4], (const float*)d_in[5],
                          (const float*)d_in[6]};
  float* out = (float*)d_out;
  const int P = in_sizes[0];

  const size_t offs[5] = {0, 8192, 40960, 172032, 696320};
  const size_t total_px = 2793472;
  size_t need = WS_TAB + total_px * sizeof(uint2);

  if (ws_size >= need && P <= 1000448) {
    float* deq = (float*)d_ws;
    float* inv = (float*)((char*)d_ws + 32);
    unsigned* partials = (unsigned*)((char*)d_ws + WS_PART);
    unsigned* hist = (unsigned*)((char*)d_ws + WS_HIST);
    unsigned* starts = (unsigned*)((char*)d_ws + WS_START);
    unsigned* cursor = (unsigned*)((char*)d_ws + WS_CURS);
    int* perm = (int*)((char*)d_ws + WS_PERM);
    float2* sxy = (float2*)((char*)d_ws + WS_SXY);
    uint2* tb = (uint2*)((char*)d_ws + WS_TAB);

    absmax_fused_kernel<<<5456, 256, 0, stream>>>(
        tabs[0], tabs[1], tabs[2], tabs[3], tabs[4], partials);
    reduce_scales_kernel<<<1, 256, 0, stream>>>(partials, deq, inv);
    quant_fused_kernel<<<10912, 256, 0, stream>>>(
        tabs[0], tabs[1], tabs[2], tabs[3], tabs[4], tb, inv);

    zero_hist_kernel<<<16, 256, 0, stream>>>(hist);
    hist_kernel<<<2048, 256, 0, stream>>>(x, y, P, hist);
    scan_kernel<<<1, 256, 0, stream>>>(hist, starts, cursor);
    scatter_kernel<<<2048, 256, 0, stream>>>(x, y, P, cursor, perm, sxy);

    int blocks = (P + 511) / 512;
    sample_kernel_sorted<<<blocks, 256, 0, stream>>>(
        sxy, perm, tb + offs[0], tb + offs[1], tb + offs[2], tb + offs[3],
        tb + offs[4], deq, out, P);
  } else {
    sample_kernel_direct<<<(P + 255) / 256, 256, 0, stream>>>(
        x, y, tabs[0], tabs[1], tabs[2], tabs[3], tabs[4], out, P);
  }
}

// Round 6
// 249.013 us; speedup vs baseline: 1.1177x; 1.1177x over previous
//
#include <hip/hip_runtime.h>

// RES=[64,128,256,512,1024], NF=8, NC=2, P=1e6. out[p*40 + lvl*8 + c], fp32.
//
// Pipeline (fused, deterministic output):
//  memset(hist)
//  K1: absmax partials (blocks [0,5456)) || point histogram (blocks [5456,7504))
//  K2: reduce scales + exclusive scan of 16384 Morton buckets (1 block)
//  K3: int8 quantize (blocks [0,10912)) || sort-scatter (blocks [10912,12960))
//  K4: sample 2 sorted points/thread, depth-2 level pipeline; wave lanes are
//      spatial neighbors (128x128 Morton buckets) -> gathers L1/L2-hit;
//      writes scatter via perm (order-independent -> deterministic).
//
// d_ws layout (bytes):
//   deq[8] f32        @ 0
//   inv[8] f32        @ 32
//   partials[5456]    @ 64
//   hist[16384]       @ 24576
//   starts[16384]     @ 90112
//   cursor[16384]     @ 155648
//   perm[P]           @ 262144
//   sortedxy[P] f2    @ 8388608
//   tables (uint2/px) @ 17301504

#define WS_PART 64
#define WS_HIST 24576
#define WS_START 90112
#define WS_CURS 155648
#define WS_PERM 262144
#define WS_SXY 8388608
#define WS_TAB 17301504
#define NBUCK 16384

__device__ __forceinline__ unsigned part1by1(unsigned v) {
  v &= 0x0000FFFFu;
  v = (v | (v << 8)) & 0x00FF00FFu;
  v = (v | (v << 4)) & 0x0F0F0F0Fu;
  v = (v | (v << 2)) & 0x33333333u;
  v = (v | (v << 1)) & 0x55555555u;
  return v;
}

__device__ __forceinline__ int bucket_of(float xv, float yv) {
  int bx = (int)(xv * 128.0f);
  int by = (int)(yv * 128.0f);
  bx = min(max(bx, 0), 127);
  by = min(max(by, 0), 127);
  return (int)(part1by1((unsigned)bx) | (part1by1((unsigned)by) << 1));
}

// ---- K1: absmax partials || histogram ----
__global__ __launch_bounds__(256) void absmax_hist_kernel(
    const float* __restrict__ s0, const float* __restrict__ s1,
    const float* __restrict__ s2, const float* __restrict__ s3,
    const float* __restrict__ s4, unsigned* __restrict__ partials,
    const float* __restrict__ x, const float* __restrict__ y, int P,
    unsigned* __restrict__ hist) {
  int b = blockIdx.x;
  if (b >= 5456) {  // histogram part
    int nb = gridDim.x - 5456;
    int stride = nb * 256;
    for (int p = (b - 5456) * 256 + (int)threadIdx.x; p < P; p += stride)
      atomicAdd(&hist[bucket_of(x[p], y[p])], 1u);
    return;
  }
  __shared__ unsigned red[4];
  const float* src; int n4; int lb; int nb;
  if (b < 16)        { src = s0; n4 = 16384;   lb = 0;    nb = 16; }
  else if (b < 80)   { src = s1; n4 = 65536;   lb = 16;   nb = 64; }
  else if (b < 336)  { src = s2; n4 = 262144;  lb = 80;   nb = 256; }
  else if (b < 1360) { src = s3; n4 = 1048576; lb = 336;  nb = 1024; }
  else               { src = s4; n4 = 4194304; lb = 1360; nb = 4096; }
  int local = b - lb;
  unsigned m = 0;
  for (int k = local * 256 + threadIdx.x; k < n4; k += nb * 256) {
    float4 v = ((const float4*)src)[k];
    unsigned a = __float_as_uint(v.x) & 0x7FFFFFFFu;
    unsigned c = __float_as_uint(v.y) & 0x7FFFFFFFu;
    unsigned d = __float_as_uint(v.z) & 0x7FFFFFFFu;
    unsigned e = __float_as_uint(v.w) & 0x7FFFFFFFu;
    m = max(m, max(max(a, c), max(d, e)));
  }
#pragma unroll
  for (int off = 32; off; off >>= 1)
    m = max(m, (unsigned)__shfl_xor((int)m, off));
  if ((threadIdx.x & 63) == 0) red[threadIdx.x >> 6] = m;
  __syncthreads();
  if (threadIdx.x == 0)
    partials[b] = max(max(red[0], red[1]), max(red[2], red[3]));
}

// ---- K2: reduce scales + scan (one block, 256 threads) ----
__global__ __launch_bounds__(256) void scales_scan_kernel(
    const unsigned* __restrict__ partials, float* __restrict__ deq,
    float* __restrict__ inv, const unsigned* __restrict__ hist,
    unsigned* __restrict__ starts, unsigned* __restrict__ cursor) {
  __shared__ unsigned red[4];
  __shared__ unsigned sums[256];
  int t = (int)threadIdx.x;
  const int lo[5] = {0, 16, 80, 336, 1360};
  const int hi[5] = {16, 80, 336, 1360, 5456};
  for (int l = 0; l < 5; ++l) {
    unsigned m = 0;
    for (int i = lo[l] + t; i < hi[l]; i += 256) m = max(m, partials[i]);
#pragma unroll
    for (int off = 32; off; off >>= 1)
      m = max(m, (unsigned)__shfl_xor((int)m, off));
    if ((t & 63) == 0) red[t >> 6] = m;
    __syncthreads();
    if (t == 0) {
      unsigned r = max(max(red[0], red[1]), max(red[2], red[3]));
      float s = __uint_as_float(r);
      if (!(s > 0.0f)) s = 1e-20f;
      deq[l] = s / 127.0f;
      inv[l] = 127.0f / s;
    }
    __syncthreads();
  }
  // exclusive scan over NBUCK=16384 (64 per thread)
  unsigned local[64];
  unsigned s = 0;
#pragma unroll
  for (int i = 0; i < 64; ++i) { local[i] = s; s += hist[t * 64 + i]; }
  sums[t] = s;
  __syncthreads();
  for (int off = 1; off < 256; off <<= 1) {
    unsigned v = (t >= off) ? sums[t - off] : 0u;
    __syncthreads();
    sums[t] += v;
    __syncthreads();
  }
  unsigned base = (t == 0) ? 0u : sums[t - 1];
#pragma unroll
  for (int i = 0; i < 64; ++i) {
    unsigned v = base + local[i];
    starts[t * 64 + i] = v;
    cursor[t * 64 + i] = v;
  }
}

// ---- K3: quantize || scatter ----
__global__ __launch_bounds__(256) void quant_scatter_kernel(
    const float* __restrict__ s0, const float* __restrict__ s1,
    const float* __restrict__ s2, const float* __restrict__ s3,
    const float* __restrict__ s4, uint2* __restrict__ tb,
    const float* __restrict__ invp,
    const float* __restrict__ x, const float* __restrict__ y, int P,
    unsigned* __restrict__ cursor, int* __restrict__ perm,
    float2* __restrict__ sxy) {
  int b = blockIdx.x;
  if (b >= 10912) {  // scatter part
    int nb = gridDim.x - 10912;
    int stride = nb * 256;
    for (int p = (b - 10912) * 256 + (int)threadIdx.x; p < P; p += stride) {
      float xv = x[p], yv = y[p];
      int bk = bucket_of(xv, yv);
      unsigned slot = atomicAdd(&cursor[bk], 1u);
      perm[slot] = p;
      sxy[slot] = make_float2(xv * 2.0f - 1.0f, yv * 2.0f - 1.0f);
    }
    return;
  }
  const float* src; int HW; int lb; int l; size_t toff;
  if (b < 32)        { src = s0; HW = 4096;    lb = 0;    l = 0; toff = 0; }
  else if (b < 160)  { src = s1; HW = 16384;   lb = 32;   l = 1; toff = 8192; }
  else if (b < 672)  { src = s2; HW = 65536;   lb = 160;  l = 2; toff = 40960; }
  else if (b < 2720) { src = s3; HW = 262144;  lb = 672;  l = 3; toff = 172032; }
  else               { src = s4; HW = 1048576; lb = 2720; l = 4; toff = 696320; }
  int i = (b - lb) * 256 + (int)threadIdx.x;
  float sc = invp[l];
  int cell = i / HW;
  int pix = i - cell * HW;
  const float* s = src + (size_t)cell * 8u * (size_t)HW + (size_t)pix;
  unsigned lov = 0, hiv = 0;
#pragma unroll
  for (int c = 0; c < 4; ++c) {
    int q = (int)rintf(s[(size_t)c * HW] * sc);
    q = min(max(q, -127), 127);
    lov |= ((unsigned)(q & 0xFF)) << (8 * c);
  }
#pragma unroll
  for (int c = 0; c < 4; ++c) {
    int q = (int)rintf(s[(size_t)(c + 4) * HW] * sc);
    q = min(max(q, -127), 127);
    hiv |= ((unsigned)(q & 0xFF)) << (8 * c);
  }
  tb[toff + (size_t)i] = make_uint2(lov, hiv);
}

// ---- sampling ----
template <int W>
__device__ __forceinline__ void level_idx(float xn, float yn, int* __restrict__ idx) {
#pragma unroll
  for (int cell = 0; cell < 2; ++cell) {
    const float off = 0.5f * (float)cell;
    float ix = (xn + 1.0f) * 0.5f * (float)(W - 1) + off;
    float iy = (yn + 1.0f) * 0.5f * (float)(W - 1) + off;
    int xi = (int)floorf(ix);
    int yi = (int)floorf(iy);
    xi = min(max(xi, 0), W - 1);
    yi = min(max(yi, 0), W - 1);
    int xb = min(xi + 1, W - 1);
    int yb = min(yi + 1, W - 1);
    int base = cell * W * W;
    idx[cell * 4 + 0] = base + yi * W + xi;
    idx[cell * 4 + 1] = base + yi * W + xb;
    idx[cell * 4 + 2] = base + yb * W + xi;
    idx[cell * 4 + 3] = base + yb * W + xb;
  }
}

template <int W>
__device__ __forceinline__ void level_weights(float xn, float yn, float* __restrict__ wgt) {
#pragma unroll
  for (int cell = 0; cell < 2; ++cell) {
    const float off = 0.5f * (float)cell;
    float ix = (xn + 1.0f) * 0.5f * (float)(W - 1) + off;
    float iy = (yn + 1.0f) * 0.5f * (float)(W - 1) + off;
    float wx = ix - floorf(ix);
    float wy = iy - floorf(iy);
    wgt[cell * 4 + 0] = (1.0f - wx) * (1.0f - wy);
    wgt[cell * 4 + 1] = wx * (1.0f - wy);
    wgt[cell * 4 + 2] = (1.0f - wx) * wy;
    wgt[cell * 4 + 3] = wx * wy;
  }
}

__device__ __forceinline__ void load8(const uint2* __restrict__ t,
                                      const int* __restrict__ idx,
                                      uint2* __restrict__ v) {
#pragma unroll
  for (int i = 0; i < 8; ++i) v[i] = t[idx[i]];
}

__device__ __forceinline__ void consume8(const uint2* __restrict__ v,
                                         const float* __restrict__ wgt, float deq,
                                         float* __restrict__ res) {
  float acc[8];
#pragma unroll
  for (int i = 0; i < 8; ++i) acc[i] = 0.0f;
#pragma unroll
  for (int i = 0; i < 8; ++i) {
    float w = wgt[i];
    unsigned lo = v[i].x, hi = v[i].y;
#pragma unroll
    for (int c = 0; c < 4; ++c)
      acc[c] = fmaf((float)(signed char)(lo >> (8 * c)), w, acc[c]);
#pragma unroll
    for (int c = 0; c < 4; ++c)
      acc[4 + c] = fmaf((float)(signed char)(hi >> (8 * c)), w, acc[4 + c]);
  }
#pragma unroll
  for (int i = 0; i < 8; ++i) res[i] = acc[i] * deq;
}

__device__ __forceinline__ void store8(float* __restrict__ o, const float* __restrict__ r) {
  ((float4*)o)[0] = make_float4(r[0], r[1], r[2], r[3]);
  ((float4*)o)[1] = make_float4(r[4], r[5], r[6], r[7]);
}

__global__ __launch_bounds__(256) void sample_kernel_sorted(
    const float2* __restrict__ sxy, const int* __restrict__ perm,
    const uint2* __restrict__ t0, const uint2* __restrict__ t1,
    const uint2* __restrict__ t2, const uint2* __restrict__ t3,
    const uint2* __restrict__ t4, const float* __restrict__ deqs,
    float* __restrict__ out, int P) {
  int i0 = blockIdx.x * 512 + (int)threadIdx.x;
  int i1 = i0 + 256;
  bool v0 = i0 < P, v1 = i1 < P;
  float2 c0 = v0 ? sxy[i0] : make_float2(0.0f, 0.0f);
  float2 c1 = v1 ? sxy[i1] : make_float2(0.0f, 0.0f);
  int q0 = v0 ? perm[i0] : 0;
  int q1 = v1 ? perm[i1] : 0;
  float xn0 = c0.x, yn0 = c0.y, xn1 = c1.x, yn1 = c1.y;
  float d0 = deqs[0], d1 = deqs[1], d2 = deqs[2], d3 = deqs[3], d4 = deqs[4];
  float* o0 = out + (size_t)q0 * 40u;
  float* o1 = out + (size_t)q1 * 40u;

  int ia[8];
  uint2 a0[8], a1[8], b0[8], b1[8];
  float wg[8], res[8];

  level_idx<64>(xn0, yn0, ia);   load8(t0, ia, a0);
  level_idx<64>(xn1, yn1, ia);   load8(t0, ia, a1);
  level_idx<128>(xn0, yn0, ia);  load8(t1, ia, b0);
  level_idx<128>(xn1, yn1, ia);  load8(t1, ia, b1);

  level_weights<64>(xn0, yn0, wg);  consume8(a0, wg, d0, res); if (v0) store8(o0 + 0, res);
  level_weights<64>(xn1, yn1, wg);  consume8(a1, wg, d0, res); if (v1) store8(o1 + 0, res);
  level_idx<256>(xn0, yn0, ia);  load8(t2, ia, a0);
  level_idx<256>(xn1, yn1, ia);  load8(t2, ia, a1);

  level_weights<128>(xn0, yn0, wg); consume8(b0, wg, d1, res); if (v0) store8(o0 + 8, res);
  level_weights<128>(xn1, yn1, wg); consume8(b1, wg, d1, res); if (v1) store8(o1 + 8, res);
  level_idx<512>(xn0, yn0, ia);  load8(t3, ia, b0);
  level_idx<512>(xn1, yn1, ia);  load8(t3, ia, b1);

  level_weights<256>(xn0, yn0, wg); consume8(a0, wg, d2, res); if (v0) store8(o0 + 16, res);
  level_weights<256>(xn1, yn1, wg); consume8(a1, wg, d2, res); if (v1) store8(o1 + 16, res);
  level_idx<1024>(xn0, yn0, ia); load8(t4, ia, a0);
  level_idx<1024>(xn1, yn1, ia); load8(t4, ia, a1);

  level_weights<512>(xn0, yn0, wg);  consume8(b0, wg, d3, res); if (v0) store8(o0 + 24, res);
  level_weights<512>(xn1, yn1, wg);  consume8(b1, wg, d3, res); if (v1) store8(o1 + 24, res);
  level_weights<1024>(xn0, yn0, wg); consume8(a0, wg, d4, res); if (v0) store8(o0 + 32, res);
  level_weights<1024>(xn1, yn1, wg); consume8(a1, wg, d4, res); if (v1) store8(o1 + 32, res);
}

// ---- fallback: native layout fp32 direct ----
template <int W>
__device__ __forceinline__ void sample_level_direct(
    const float* __restrict__ t, float xv, float yv, float* __restrict__ o) {
  float acc[8];
#pragma unroll
  for (int i = 0; i < 8; ++i) acc[i] = 0.0f;
  float xn = xv * 2.0f - 1.0f;
  float yn = yv * 2.0f - 1.0f;
#pragma unroll
  for (int cell = 0; cell < 2; ++cell) {
    const float off = 0.5f * (float)cell;
    float ix = (xn + 1.0f) * 0.5f * (float)(W - 1) + off;
    float iy = (yn + 1.0f) * 0.5f * (float)(W - 1) + off;
    float x0f = floorf(ix), y0f = floorf(iy);
    float wx = ix - x0f, wy = iy - y0f;
    int x0 = (int)x0f; x0 = min(max(x0, 0), W - 1);
    int y0 = (int)y0f; y0 = min(max(y0, 0), W - 1);
    int x1 = min(x0 + 1, W - 1);
    int y1 = min(y0 + 1, W - 1);
    float w00 = (1.0f - wx) * (1.0f - wy);
    float w01 = wx * (1.0f - wy);
    float w10 = (1.0f - wx) * wy;
    float w11 = wx * wy;
    const float* b = t + (size_t)cell * 8u * (size_t)W * (size_t)W;
    size_t i00 = (size_t)y0 * W + x0;
    size_t i01 = (size_t)y0 * W + x1;
    size_t i10 = (size_t)y1 * W + x0;
    size_t i11 = (size_t)y1 * W + x1;
#pragma unroll
    for (int c = 0; c < 8; ++c) {
      const float* pc = b + (size_t)c * (size_t)W * (size_t)W;
      acc[c] += pc[i00] * w00 + pc[i01] * w01 + pc[i10] * w10 + pc[i11] * w11;
    }
  }
#pragma unroll
  for (int i = 0; i < 8; ++i) o[i] = acc[i];
}

__global__ __launch_bounds__(256) void sample_kernel_direct(
    const float* __restrict__ x, const float* __restrict__ y,
    const float* __restrict__ t0, const float* __restrict__ t1,
    const float* __restrict__ t2, const float* __restrict__ t3,
    const float* __restrict__ t4, float* __restrict__ out, int P) {
  int p = blockIdx.x * blockDim.x + threadIdx.x;
  if (p >= P) return;
  float xv = x[p];
  float yv = y[p];
  float o[8];
  float* orow = out + (size_t)p * 40u;
  sample_level_direct<64>(t0, xv, yv, o);
#pragma unroll
  for (int i = 0; i < 8; ++i) orow[0 + i] = o[i];
  sample_level_direct<128>(t1, xv, yv, o);
#pragma unroll
  for (int i = 0; i < 8; ++i) orow[8 + i] = o[i];
  sample_level_direct<256>(t2, xv, yv, o);
#pragma unroll
  for (int i = 0; i < 8; ++i) orow[16 + i] = o[i];
  sample_level_direct<512>(t3, xv, yv, o);
#pragma unroll
  for (int i = 0; i < 8; ++i) orow[24 + i] = o[i];
  sample_level_direct<1024>(t4, xv, yv, o);
#pragma unroll
  for (int i = 0; i < 8; ++i) orow[32 + i] = o[i];
}

extern "C" void kernel_launch(void* const* d_in, const int* in_sizes, int n_in,
                              void* d_out, int out_size, void* d_ws, size_t ws_size,
                              hipStream_t stream) {
  const float* x = (const float*)d_in[0];
  const float* y = (const float*)d_in[1];
  const float* tabs[5] = {(const float*)d_in[2], (const float*)d_in[3],
                          (const float*)d_in[4], (const float*)d_in[5],
                          (const float*)d_in[6]};
  float* out = (float*)d_out;
  const int P = in_sizes[0];

  const size_t offs[5] = {0, 8192, 40960, 172032, 696320};
  const size_t total_px = 2793472;
  size_t need = WS_TAB + total_px * sizeof(uint2);

  if (ws_size >= need && P <= 1000448) {
    float* deq = (float*)d_ws;
    float* inv = (float*)((char*)d_ws + 32);
    unsigned* partials = (unsigned*)((char*)d_ws + WS_PART);
    unsigned* hist = (unsigned*)((char*)d_ws + WS_HIST);
    unsigned* starts = (unsigned*)((char*)d_ws + WS_START);
    unsigned* cursor = (unsigned*)((char*)d_ws + WS_CURS);
    int* perm = (int*)((char*)d_ws + WS_PERM);
    float2* sxy = (float2*)((char*)d_ws + WS_SXY);
    uint2* tb = (uint2*)((char*)d_ws + WS_TAB);

    hipMemsetAsync(hist, 0, NBUCK * sizeof(unsigned), stream);
    absmax_hist_kernel<<<5456 + 2048, 256, 0, stream>>>(
        tabs[0], tabs[1], tabs[2], tabs[3], tabs[4], partials, x, y, P, hist);
    scales_scan_kernel<<<1, 256, 0, stream>>>(partials, deq, inv, hist, starts,
                                              cursor);
    quant_scatter_kernel<<<10912 + 2048, 256, 0, stream>>>(
        tabs[0], tabs[1], tabs[2], tabs[3], tabs[4], tb, inv, x, y, P, cursor,
        perm, sxy);
    int blocks = (P + 511) / 512;
    sample_kernel_sorted<<<blocks, 256, 0, stream>>>(
        sxy, perm, tb + offs[0], tb + offs[1], tb + offs[2], tb + offs[3],
        tb + offs[4], deq, out, P);
  } else {
    sample_kernel_direct<<<(P + 255) / 256, 256, 0, stream>>>(
        x, y, tabs[0], tabs[1], tabs[2], tabs[3], tabs[4], out, P);
  }
}